// Round 7
// baseline (1036.550 us; speedup 1.0000x reference)
//
#include <hip/hip_runtime.h>
#include <hip/hip_bf16.h>
#include <stdint.h>

// Problem constants: A=2048 agents, H=128, G=8 (64 cells), NB=32, CELL=8
// pooled = (grid[A,64,128] flattened) @ W.T + b ; out masked by valid_i.

typedef __attribute__((ext_vector_type(4))) float f32x4;
typedef __attribute__((ext_vector_type(8))) short short8;

// workspace layout (bytes)
#define O_HB   0u          // bf16 hidden [2049][128]  (row 2048 = zeros, dummy target)
#define O_WB   1048576u    // bf16 W      [128][8192]
#define O_GRID 3145728u    // bf16 grid   [2048][8192]
#define O_PART 36700160u   // f32 partials [16][2048][128]
#define O_POSM 36700160u   // float2 posm[2048] (16KB) -- overlaps part: written by prep,
                           // read by build, then gemm overwrites. Deterministic per launch.
// total ~51 MB

__device__ __forceinline__ void gl_lds16(const void* g, void* l) {
  __builtin_amdgcn_global_load_lds((const __attribute__((address_space(1))) void*)g,
                                   (__attribute__((address_space(3))) void*)l, 16, 0, 0);
}

__device__ __forceinline__ float bf_lo(uint32_t w) {
  union { uint32_t u; float f; } v{w << 16}; return v.f;
}
__device__ __forceinline__ float bf_hi(uint32_t w) {
  union { uint32_t u; float f; } v{w & 0xffff0000u}; return v.f;
}
__device__ __forceinline__ uint32_t pack_bf2(float x, float y) {
  __hip_bfloat16 bx = __float2bfloat16(x), by = __float2bfloat16(y);
  return ((uint32_t)(*(unsigned short*)&by) << 16) | (*(unsigned short*)&bx);
}

// ---------------- prep: f32 -> bf16 conversions + NaN-poisoned posm ----------------
__global__ __launch_bounds__(256) void sp_prep(const float* __restrict__ hidden,
                                               const float* __restrict__ W,
                                               const float* __restrict__ pos,
                                               const int* __restrict__ mask,
                                               __hip_bfloat16* __restrict__ hb,
                                               __hip_bfloat16* __restrict__ wb,
                                               float2* __restrict__ posm) {
  int idx = blockIdx.x * 256 + threadIdx.x;
  const int HID4 = (2049 * 128) / 4;   // 65568 groups of 4
  const int W4   = (128 * 8192) / 4;   // 262144 groups of 4
  if (idx < HID4) {
    int e = idx * 4;
    float4 v = make_float4(0.f, 0.f, 0.f, 0.f);
    if (e < 2048 * 128) v = *reinterpret_cast<const float4*>(hidden + e);
    ushort4 pk;
    pk.x = (ushort)(pack_bf2(v.x, v.x) & 0xffffu);
    pk.y = (ushort)(pack_bf2(v.y, v.y) & 0xffffu);
    pk.z = (ushort)(pack_bf2(v.z, v.z) & 0xffffu);
    pk.w = (ushort)(pack_bf2(v.w, v.w) & 0xffffu);
    *reinterpret_cast<ushort4*>(hb + e) = pk;
  } else if (idx < HID4 + W4) {
    int e = (idx - HID4) * 4;
    float4 v = *reinterpret_cast<const float4*>(W + e);
    ushort4 pk;
    pk.x = (ushort)(pack_bf2(v.x, v.x) & 0xffffu);
    pk.y = (ushort)(pack_bf2(v.y, v.y) & 0xffffu);
    pk.z = (ushort)(pack_bf2(v.z, v.z) & 0xffffu);
    pk.w = (ushort)(pack_bf2(v.w, v.w) & 0xffffu);
    *reinterpret_cast<ushort4*>(wb + e) = pk;
  } else {
    int j = idx - (HID4 + W4);
    if (j < 2048) {
      float2 p = reinterpret_cast<const float2*>(pos)[j];
      union { uint32_t u; float f; } qn{0x7fc00000u};  // quiet NaN
      float2 o;
      bool m = (mask[j] != 0);
      o.x = m ? p.x : qn.f;
      o.y = m ? p.y : qn.f;
      posm[j] = o;
    }
  }
}

// ---------------- build: unordered list + LDS f32-atomic accumulator ----------------
// 512 threads (8 waves), one agent per block. No counting sort, no per-cell
// segments, no per-cell register chains.
//   Phase A: bin j's, ballot-compact (j<<8|c) into an UNORDERED list; zero accs.
//   Phase D: per 4-entry group: half-wave hi5 serves entries k+hi5 / k+2+hi5;
//     one dwordx2 gather per 2 rows; 4 ds_add_f32 (atomic, return-less) into
//     accs[c][r][lq ^ ((c&7)<<2)] -- bank-conflict-free by construction; fully
//     independent iterations + 1-ahead pipeline => >=4 loads in flight.
//   Epilogue: unswizzle accs, pack bf16, coalesced grid write.
__global__ __launch_bounds__(512) void sp_build(const float* __restrict__ pos,
                                                const float2* __restrict__ posm,
                                                const __hip_bfloat16* __restrict__ hb,
                                                __hip_bfloat16* __restrict__ grid) {
  __shared__ float accs[8192];            // logical [c][r][32], r = col&3, swizzled lq
  __shared__ uint32_t list32[2080];       // (j<<8)|c, unordered; dummy = 2048<<8
  __shared__ int nTot;
  int t = threadIdx.x;
  int i = blockIdx.x;
  int lane = t & 63;
  int wv = t >> 6;
  if (t == 0) nTot = 0;
  #pragma unroll
  for (int q = 0; q < 4; ++q)
    *reinterpret_cast<float4*>(&accs[(t + q * 512) * 4]) = make_float4(0.f, 0.f, 0.f, 0.f);
  __syncthreads();
  float pxi = pos[2 * i], pyi = pos[2 * i + 1];
  #pragma unroll
  for (int jj = 0; jj < 4; ++jj) {
    int j = t + jj * 512;
    float2 pj = posm[j];
    float rx = pj.x - pxi, ry = pj.y - pyi;
    // NaN rel (masked-out j or NaN pos) -> comparisons false -> invalid
    bool ok = (fabsf(rx) < 32.f) && (fabsf(ry) < 32.f) && (j != i);
    uint32_t e = 0;
    if (ok) {
      // rx,ry in (-32,32): (rx+32)*0.125 in [0,8) exactly; clip is a no-op
      int col = (int)floorf((rx + 32.f) * 0.125f);
      int row = (int)floorf((ry + 32.f) * 0.125f);
      e = ((uint32_t)j << 8) | (uint32_t)(row * 8 + col);
    }
    unsigned long long mb = __ballot(ok);
    int cnt = __popcll(mb);
    int pre = __popcll(mb & ((1ull << lane) - 1ull));
    int base = 0;
    if (lane == 0) base = cnt ? atomicAdd(&nTot, cnt) : 0;
    base = __shfl(base, 0);
    if (ok) list32[base + pre] = e;
  }
  __syncthreads();
  int N = nTot;
  int Npad = (N + 31) & ~31;
  if (t < Npad - N) list32[N + t] = (2048u << 8);   // dummy -> zero row, cell 0
  __syncthreads();
  // Phase D
  int hi5 = lane >> 5;          // which entry of the pair this half-wave serves
  int lq = lane & 31;           // dword-pair (cols 4lq..4lq+3) within a row
  int lqoff = lq * 8;
  int lsw[8];                   // unused placeholder removed
  (void)lsw;
  const char* hbB = reinterpret_cast<const char*>(hb);
  const uint32_t DUM = (2048u << 8);
  int k = wv * 4;
  uint32_t ea0 = DUM, ea1 = DUM;
  uint2 da0 = make_uint2(0u, 0u), da1 = make_uint2(0u, 0u);
  if (k < Npad) {
    ea0 = list32[k + hi5];
    ea1 = list32[k + 2 + hi5];
    da0 = *reinterpret_cast<const uint2*>(hbB + (ea0 & 0xFFFFFF00u) + lqoff);
    da1 = *reinterpret_cast<const uint2*>(hbB + (ea1 & 0xFFFFFF00u) + lqoff);
  }
  for (; k < Npad; k += 32) {
    int kn = k + 32;
    uint32_t eb0 = DUM, eb1 = DUM;
    uint2 db0 = da0, db1 = da1;
    if (kn < Npad) {
      eb0 = list32[kn + hi5];
      eb1 = list32[kn + 2 + hi5];
      db0 = *reinterpret_cast<const uint2*>(hbB + (eb0 & 0xFFFFFF00u) + lqoff);
      db1 = *reinterpret_cast<const uint2*>(hbB + (eb1 & 0xFFFFFF00u) + lqoff);
    }
    {
      int c = (int)(ea0 & 63u);
      int bi = (c << 7) + (lq ^ ((c & 7) << 2));
      atomicAdd(&accs[bi +  0], bf_lo(da0.x));
      atomicAdd(&accs[bi + 32], bf_hi(da0.x));
      atomicAdd(&accs[bi + 64], bf_lo(da0.y));
      atomicAdd(&accs[bi + 96], bf_hi(da0.y));
    }
    {
      int c = (int)(ea1 & 63u);
      int bi = (c << 7) + (lq ^ ((c & 7) << 2));
      atomicAdd(&accs[bi +  0], bf_lo(da1.x));
      atomicAdd(&accs[bi + 32], bf_hi(da1.x));
      atomicAdd(&accs[bi + 64], bf_lo(da1.y));
      atomicAdd(&accs[bi + 96], bf_hi(da1.y));
    }
    ea0 = eb0; ea1 = eb1; da0 = db0; da1 = db1;
  }
  __syncthreads();
  // Epilogue: thread -> (c, m): cols 16m..16m+15; read[r][q] = col 16m+4q+r
  {
    int c = t >> 3, m = t & 7;
    int mb4 = 4 * (m ^ (c & 7));          // swizzled lq-group base
    int baseI = (c << 7) + mb4;
    float4 q0 = *reinterpret_cast<const float4*>(&accs[baseI +  0]);
    float4 q1 = *reinterpret_cast<const float4*>(&accs[baseI + 32]);
    float4 q2 = *reinterpret_cast<const float4*>(&accs[baseI + 64]);
    float4 q3 = *reinterpret_cast<const float4*>(&accs[baseI + 96]);
    uint4 o0, o1;
    o0.x = pack_bf2(q0.x, q1.x);   // cols 16m+0,1
    o0.y = pack_bf2(q2.x, q3.x);   // cols 16m+2,3
    o0.z = pack_bf2(q0.y, q1.y);   // cols 16m+4,5
    o0.w = pack_bf2(q2.y, q3.y);   // cols 16m+6,7
    o1.x = pack_bf2(q0.z, q1.z);   // cols 16m+8,9
    o1.y = pack_bf2(q2.z, q3.z);   // cols 16m+10,11
    o1.z = pack_bf2(q0.w, q1.w);   // cols 16m+12,13
    o1.w = pack_bf2(q2.w, q3.w);   // cols 16m+14,15
    char* gp = reinterpret_cast<char*>(grid) + ((size_t)i << 14) + (size_t)(c * 256 + m * 32);
    *reinterpret_cast<uint4*>(gp) = o0;
    *reinterpret_cast<uint4*>(gp + 16) = o1;
  }
}

// ---------------- gemm: [2048 x 8192] bf16 @ W[n][k] bf16 -> f32 partials (split-K 16) ----------------
// BM=64, BN=128, BK=64; 4 waves, wave-tile 32x64; mfma_f32_16x16x32_bf16
// LDS rows are 128 B = 8 x 16B granules; XOR-swizzle granule with (row&7):
// stage source pre-swizzled (linear LDS dest, per global_load_lds constraint), read with same XOR.
__global__ __launch_bounds__(256) void sp_gemm(const __hip_bfloat16* __restrict__ Ag,
                                               const __hip_bfloat16* __restrict__ Wb,
                                               float* __restrict__ part) {
  __shared__ __align__(16) char Asm[8192];    // A tile [64][64] bf16
  __shared__ __align__(16) char Bsm[16384];   // B tile [128][64] bf16 (n-major)
  int t = threadIdx.x;
  int lane = t & 63;
  int w = t >> 6;
  int wm = w >> 1, wn = w & 1;
  int bx = blockIdx.x;
  int mt = bx & 31;     // 32 M-tiles of 64 rows
  int sp = bx >> 5;     // 16 K-splits of 512
  int i0 = mt * 64;
  long kbase = (long)sp * 512 * 2;  // byte offset of K-chunk within a row
  const char* Agc = (const char*)Ag;
  const char* Wbc = (const char*)Wb;
  f32x4 acc[2][4] = {};
  for (int st = 0; st < 8; ++st) {   // 8 K-steps of 64
    long kb = kbase + st * 128;
    #pragma unroll
    for (int q = 0; q < 2; ++q) {    // A: 8 KB
      int o = (q * 256 + t) * 16;
      int r = o >> 7;
      int sc = (o & 127) ^ ((r & 7) << 4);
      gl_lds16(Agc + (long)(i0 + r) * 16384 + kb + sc, Asm + o);
    }
    #pragma unroll
    for (int q = 0; q < 4; ++q) {    // B: 16 KB
      int o = (q * 256 + t) * 16;
      int r = o >> 7;
      int sc = (o & 127) ^ ((r & 7) << 4);
      gl_lds16(Wbc + (long)r * 16384 + kb + sc, Bsm + o);
    }
    __syncthreads();
    short8 af[2][2], bfr[4][2];
    #pragma unroll
    for (int fr = 0; fr < 2; ++fr)
      #pragma unroll
      for (int ks = 0; ks < 2; ++ks) {
        int r = wm * 32 + fr * 16 + (lane & 15);
        int g = ks * 4 + (lane >> 4);
        int byt = r * 128 + ((g ^ (r & 7)) << 4);
        af[fr][ks] = *reinterpret_cast<const short8*>(Asm + byt);
      }
    #pragma unroll
    for (int fc = 0; fc < 4; ++fc)
      #pragma unroll
      for (int ks = 0; ks < 2; ++ks) {
        int n = wn * 64 + fc * 16 + (lane & 15);
        int g = ks * 4 + (lane >> 4);
        int byt = n * 128 + ((g ^ (n & 7)) << 4);
        bfr[fc][ks] = *reinterpret_cast<const short8*>(Bsm + byt);
      }
    #pragma unroll
    for (int fr = 0; fr < 2; ++fr)
      #pragma unroll
      for (int fc = 0; fc < 4; ++fc)
        #pragma unroll
        for (int ks = 0; ks < 2; ++ks)
          acc[fr][fc] = __builtin_amdgcn_mfma_f32_16x16x32_bf16(af[fr][ks], bfr[fc][ks],
                                                                acc[fr][fc], 0, 0, 0);
    __syncthreads();
  }
  float* p = part + (long)sp * 262144;
  #pragma unroll
  for (int fr = 0; fr < 2; ++fr)
    #pragma unroll
    for (int fc = 0; fc < 4; ++fc)
      #pragma unroll
      for (int r4 = 0; r4 < 4; ++r4) {
        int ii = i0 + wm * 32 + fr * 16 + (lane >> 4) * 4 + r4;  // C/D: row=(lane>>4)*4+reg
        int nn = wn * 64 + fc * 16 + (lane & 15);                 // C/D: col=lane&15
        p[(long)ii * 128 + nn] = acc[fr][fc][r4];
      }
}

// ---------------- reduce: sum 16 partials + bias, apply valid_i mask ----------------
__global__ __launch_bounds__(256) void sp_reduce(const float* __restrict__ part,
                                                 const float* __restrict__ bias,
                                                 const float* __restrict__ pos,
                                                 const int* __restrict__ mask,
                                                 float* __restrict__ out) {
  int g = blockIdx.x * 256 + threadIdx.x;  // 0..262143
  int i = g >> 7, n = g & 127;
  float acc = bias[n];
  #pragma unroll
  for (int s = 0; s < 16; ++s) acc += part[(long)s * 262144 + g];
  float px = pos[2 * i], py = pos[2 * i + 1];
  bool vi = (mask[i] != 0) && (px == px) && (py == py);  // mask & ~isnan(pos).any
  out[g] = vi ? acc : 0.f;
}

extern "C" void kernel_launch(void* const* d_in, const int* in_sizes, int n_in,
                              void* d_out, int out_size, void* d_ws, size_t ws_size,
                              hipStream_t stream) {
  const float* hidden  = (const float*)d_in[0];
  const float* pos     = (const float*)d_in[1];
  const int*   mask    = (const int*)d_in[2];   // bool input -> int32 per harness contract
  const float* W       = (const float*)d_in[3];
  const float* bias    = (const float*)d_in[4];
  char* ws = (char*)d_ws;
  __hip_bfloat16* hb   = (__hip_bfloat16*)(ws + O_HB);
  __hip_bfloat16* wb   = (__hip_bfloat16*)(ws + O_WB);
  __hip_bfloat16* grid = (__hip_bfloat16*)(ws + O_GRID);
  float* part          = (float*)(ws + O_PART);
  float2* posm         = (float2*)(ws + O_POSM);
  float* out           = (float*)d_out;

  sp_prep<<<1289, 256, 0, stream>>>(hidden, W, pos, mask, hb, wb, posm);
  sp_build<<<2048, 512, 0, stream>>>(pos, posm, hb, grid);
  sp_gemm<<<512, 256, 0, stream>>>(grid, wb, part);
  sp_reduce<<<1024, 256, 0, stream>>>(part, bias, pos, mask, out);
}

// Round 8
// 92.048 us; speedup vs baseline: 11.2610x; 11.2610x over previous
//
#include <hip/hip_runtime.h>
#include <hip/hip_bf16.h>
#include <stdint.h>

// Problem constants: A=2048 agents, H=128, G=8 (64 cells), NB=32, CELL=8
// pooled = (grid[A,64,128] flattened) @ W.T + b ; out masked by valid_i.

typedef __attribute__((ext_vector_type(4))) float f32x4;
typedef __attribute__((ext_vector_type(8))) short short8;

// workspace layout (bytes)
#define O_HB   0u          // bf16 hidden [2049][128]  (row 2048 = zeros, dummy target)
#define O_WB   1048576u    // bf16 W      [128][8192]
#define O_GRID 3145728u    // bf16 grid   [2048][8192]
#define O_PART 36700160u   // f32 partials [16][2048][128]
#define O_POSM 36700160u   // float2 posm[2048] (16KB) -- overlaps part: written by prep,
                           // read by build, then gemm overwrites. Deterministic per launch.
// total ~51 MB

__device__ __forceinline__ void gl_lds16(const void* g, void* l) {
  __builtin_amdgcn_global_load_lds((const __attribute__((address_space(1))) void*)g,
                                   (__attribute__((address_space(3))) void*)l, 16, 0, 0);
}

__device__ __forceinline__ float bf_lo(uint32_t w) {
  union { uint32_t u; float f; } v{w << 16}; return v.f;
}
__device__ __forceinline__ float bf_hi(uint32_t w) {
  union { uint32_t u; float f; } v{w & 0xffff0000u}; return v.f;
}
__device__ __forceinline__ uint32_t pack_bf2(float x, float y) {
  __hip_bfloat16 bx = __float2bfloat16(x), by = __float2bfloat16(y);
  return ((uint32_t)(*(unsigned short*)&by) << 16) | (*(unsigned short*)&bx);
}

// ---------------- prep: f32 -> bf16 conversions + NaN-poisoned posm ----------------
__global__ __launch_bounds__(256) void sp_prep(const float* __restrict__ hidden,
                                               const float* __restrict__ W,
                                               const float* __restrict__ pos,
                                               const int* __restrict__ mask,
                                               __hip_bfloat16* __restrict__ hb,
                                               __hip_bfloat16* __restrict__ wb,
                                               float2* __restrict__ posm) {
  int idx = blockIdx.x * 256 + threadIdx.x;
  const int HID4 = (2049 * 128) / 4;   // 65568 groups of 4
  const int W4   = (128 * 8192) / 4;   // 262144 groups of 4
  if (idx < HID4) {
    int e = idx * 4;
    float4 v = make_float4(0.f, 0.f, 0.f, 0.f);
    if (e < 2048 * 128) v = *reinterpret_cast<const float4*>(hidden + e);
    ushort4 pk;
    pk.x = (ushort)(pack_bf2(v.x, v.x) & 0xffffu);
    pk.y = (ushort)(pack_bf2(v.y, v.y) & 0xffffu);
    pk.z = (ushort)(pack_bf2(v.z, v.z) & 0xffffu);
    pk.w = (ushort)(pack_bf2(v.w, v.w) & 0xffffu);
    *reinterpret_cast<ushort4*>(hb + e) = pk;
  } else if (idx < HID4 + W4) {
    int e = (idx - HID4) * 4;
    float4 v = *reinterpret_cast<const float4*>(W + e);
    ushort4 pk;
    pk.x = (ushort)(pack_bf2(v.x, v.x) & 0xffffu);
    pk.y = (ushort)(pack_bf2(v.y, v.y) & 0xffffu);
    pk.z = (ushort)(pack_bf2(v.z, v.z) & 0xffffu);
    pk.w = (ushort)(pack_bf2(v.w, v.w) & 0xffffu);
    *reinterpret_cast<ushort4*>(wb + e) = pk;
  } else {
    int j = idx - (HID4 + W4);
    if (j < 2048) {
      float2 p = reinterpret_cast<const float2*>(pos)[j];
      union { uint32_t u; float f; } qn{0x7fc00000u};  // quiet NaN
      float2 o;
      bool m = (mask[j] != 0);
      o.x = m ? p.x : qn.f;
      o.y = m ? p.y : qn.f;
      posm[j] = o;
    }
  }
}

// ---------------- build: wave-private counting sort + scalarized pipelined gather ------
// 4 waves/block, ONE AGENT PER WAVE, everything wave-private (NO barriers, NO float
// atomics). Counting sort pads each cell to x2 so a row-pair never straddles cells.
// Gather: batches of 16 rows = 8 global_load_dwordx2 (lanes 0-31 row A, 32-63 row B);
// entries read UNIFORM (ds_read_b128 broadcast, 2 batches ahead, readfirstlane ->
// scalar row bases); batch b+1 issues BEFORE batch b is consumed -> counted vmcnt(8),
// ~4KB in flight per wave. Cell flush: shfl_xor(32) combine + coalesced 256B store
// (empty cells flush zeros -> full grid coverage).
#define FLUSH_CELL()                                                        \
  {                                                                         \
    float d0 = a0 + __shfl_xor(a0, 32);                                     \
    float d1 = a1 + __shfl_xor(a1, 32);                                     \
    float d2 = a2 + __shfl_xor(a2, 32);                                     \
    float d3 = a3 + __shfl_xor(a3, 32);                                     \
    if (loA) {                                                              \
      uint2 pk; pk.x = pack_bf2(d0, d1); pk.y = pack_bf2(d2, d3);           \
      *reinterpret_cast<uint2*>(gbase + (c << 8) + laneoff) = pk;           \
    }                                                                       \
    a0 = a1 = a2 = a3 = 0.f;                                                \
  }

#define ISSUE_PAIR(Ldst, sdexpr)                                            \
  {                                                                         \
    int sd_ = __builtin_amdgcn_readfirstlane(sdexpr);                       \
    uint32_t oA_ = (uint32_t)(sd_ & 0xffff) << 8;                           \
    uint32_t oB_ = ((uint32_t)sd_ >> 16) << 8;                              \
    uint32_t sel_ = loA ? oA_ : oB_;                                        \
    Ldst = *reinterpret_cast<const uint2*>(hbB + sel_ + laneoff);           \
  }

#define ISSUE_BATCH(L, Ea, Eb)                                              \
  ISSUE_PAIR(L[0], Ea.x) ISSUE_PAIR(L[1], Ea.y)                             \
  ISSUE_PAIR(L[2], Ea.z) ISSUE_PAIR(L[3], Ea.w)                             \
  ISSUE_PAIR(L[4], Eb.x) ISSUE_PAIR(L[5], Eb.y)                             \
  ISSUE_PAIR(L[6], Eb.z) ISSUE_PAIR(L[7], Eb.w)

#define CONSUME_PAIR(Lp)                                                    \
  {                                                                         \
    while (c < 64 && rpos == bnd) {                                         \
      FLUSH_CELL();                                                         \
      ++c;                                                                  \
      bnd = (c < 64) ? __builtin_amdgcn_readlane(bndv, c) : 0x7fffffff;     \
    }                                                                       \
    uint2 w_ = Lp;                                                          \
    a0 += bf_lo(w_.x); a1 += bf_hi(w_.x);                                   \
    a2 += bf_lo(w_.y); a3 += bf_hi(w_.y);                                   \
    rpos += 2;                                                              \
  }

__global__ __launch_bounds__(256) void sp_build(const float* __restrict__ pos,
                                                const float2* __restrict__ posm,
                                                const __hip_bfloat16* __restrict__ hb,
                                                __hip_bfloat16* __restrict__ grid) {
  __shared__ __align__(16) uint16_t lists[4][2240];  // wave-private cell-sorted j list
  __shared__ int hist[4][64];
  __shared__ int curs[4][64];
  int t = threadIdx.x;
  int wv = t >> 6;
  int lane = t & 63;
  int i = blockIdx.x * 4 + wv;           // this wave's agent
  bool loA = lane < 32;
  uint32_t laneoff = (uint32_t)(lane & 31) * 8;

  float pxi = pos[2 * i], pyi = pos[2 * i + 1];
  hist[wv][lane] = 0;
  // init list to dummy pairs (j=2048 -> zero row of hb)
  const uint32_t DUMW = 0x08000800u;
  #pragma unroll
  for (int q = 0; q < 18; ++q) {
    int d = lane + q * 64;
    if (d < 1120) reinterpret_cast<uint32_t*>(lists[wv])[d] = DUMW;
  }
  // Phase A: bin all 2048 j's, pack bins into 8 regs (4 bytes each, static idx)
  uint32_t bp[8];
  #pragma unroll
  for (int r = 0; r < 8; ++r) bp[r] = 0;
  #pragma unroll
  for (int ch = 0; ch < 32; ++ch) {
    int j = ch * 64 + lane;
    float2 pj = posm[j];
    float rx = pj.x - pxi, ry = pj.y - pyi;
    // NaN rel (masked-out j or NaN pos) -> comparisons false -> invalid
    bool ok = (fabsf(rx) < 32.f) && (fabsf(ry) < 32.f) && (j != i);
    uint32_t b = 255;
    if (ok) {
      // rx,ry in (-32,32): (rx+32)*0.125 in [0,8) exactly; clip is a no-op
      int col = (int)floorf((rx + 32.f) * 0.125f);
      int row = (int)floorf((ry + 32.f) * 0.125f);
      b = (uint32_t)(row * 8 + col);
      atomicAdd(&hist[wv][b], 1);       // int LDS atomic: native, fast
    }
    bp[ch >> 2] |= b << ((ch & 3) * 8);
  }
  // Phase B: wave-private scan over x2-padded cell counts (lane = cell)
  int h = hist[wv][lane];
  int pc = (h + 1) & ~1;                 // pad cells to even length
  int x = pc;
  #pragma unroll
  for (int d = 1; d < 64; d <<= 1) {
    int y = __shfl_up(x, d);
    if (lane >= d) x += y;
  }
  int bndv = x;                          // lane l holds offs[l+1]
  curs[wv][lane] = x - pc;               // cell start cursor
  int listLen = __builtin_amdgcn_readlane(bndv, 63);
  // Phase C: scatter (intra-wave int atomics only)
  #pragma unroll
  for (int ch = 0; ch < 32; ++ch) {
    uint32_t b = (bp[ch >> 2] >> ((ch & 3) * 8)) & 255u;
    if (b != 255u) {
      int slot = atomicAdd(&curs[wv][b], 1);
      lists[wv][slot] = (uint16_t)(ch * 64 + lane);
    }
  }
  // Phase D: batch-16 pipelined gather
  int Npad = (listLen + 15) & ~15;
  int nb = Npad >> 4;
  const char* hbB = reinterpret_cast<const char*>(hb);
  char* gbase = reinterpret_cast<char*>(grid) + ((size_t)i << 14);
  float a0 = 0.f, a1 = 0.f, a2 = 0.f, a3 = 0.f;
  int c = 0;
  int bnd = __builtin_amdgcn_readlane(bndv, 0);
  int rpos = 0;
  const char* lw = reinterpret_cast<const char*>(lists[wv]);
  uint2 Lc[8], Ln[8];
  // prologue: entries batch0 -> issue; preload entries batch1
  int4 E0a = *reinterpret_cast<const int4*>(lw + 0);
  int4 E0b = *reinterpret_cast<const int4*>(lw + 16);
  ISSUE_BATCH(Lc, E0a, E0b)
  int4 EiA = *reinterpret_cast<const int4*>(lw + 32);
  int4 EiB = *reinterpret_cast<const int4*>(lw + 48);
  for (int b = 0; b < nb; ++b) {
    int eoff = (b + 2) * 32;
    int4 ErA = *reinterpret_cast<const int4*>(lw + eoff);
    int4 ErB = *reinterpret_cast<const int4*>(lw + eoff + 16);
    if (b + 1 < nb) { ISSUE_BATCH(Ln, EiA, EiB) }
    CONSUME_PAIR(Lc[0]) CONSUME_PAIR(Lc[1]) CONSUME_PAIR(Lc[2]) CONSUME_PAIR(Lc[3])
    CONSUME_PAIR(Lc[4]) CONSUME_PAIR(Lc[5]) CONSUME_PAIR(Lc[6]) CONSUME_PAIR(Lc[7])
    #pragma unroll
    for (int p = 0; p < 8; ++p) Lc[p] = Ln[p];
    EiA = ErA; EiB = ErB;
  }
  // drain remaining cell flushes (covers empty tail cells; writes zeros)
  while (c < 64) {
    FLUSH_CELL();
    ++c;
  }
}

// ---------------- gemm: [2048 x 8192] bf16 @ W[n][k] bf16 -> f32 partials (split-K 16) ----------------
// BM=64, BN=128, BK=64; 4 waves, wave-tile 32x64; mfma_f32_16x16x32_bf16
// LDS rows are 128 B = 8 x 16B granules; XOR-swizzle granule with (row&7):
// stage source pre-swizzled (linear LDS dest, per global_load_lds constraint), read with same XOR.
__global__ __launch_bounds__(256) void sp_gemm(const __hip_bfloat16* __restrict__ Ag,
                                               const __hip_bfloat16* __restrict__ Wb,
                                               float* __restrict__ part) {
  __shared__ __align__(16) char Asm[8192];    // A tile [64][64] bf16
  __shared__ __align__(16) char Bsm[16384];   // B tile [128][64] bf16 (n-major)
  int t = threadIdx.x;
  int lane = t & 63;
  int w = t >> 6;
  int wm = w >> 1, wn = w & 1;
  int bx = blockIdx.x;
  int mt = bx & 31;     // 32 M-tiles of 64 rows
  int sp = bx >> 5;     // 16 K-splits of 512
  int i0 = mt * 64;
  long kbase = (long)sp * 512 * 2;  // byte offset of K-chunk within a row
  const char* Agc = (const char*)Ag;
  const char* Wbc = (const char*)Wb;
  f32x4 acc[2][4] = {};
  for (int st = 0; st < 8; ++st) {   // 8 K-steps of 64
    long kb = kbase + st * 128;
    #pragma unroll
    for (int q = 0; q < 2; ++q) {    // A: 8 KB
      int o = (q * 256 + t) * 16;
      int r = o >> 7;
      int sc = (o & 127) ^ ((r & 7) << 4);
      gl_lds16(Agc + (long)(i0 + r) * 16384 + kb + sc, Asm + o);
    }
    #pragma unroll
    for (int q = 0; q < 4; ++q) {    // B: 16 KB
      int o = (q * 256 + t) * 16;
      int r = o >> 7;
      int sc = (o & 127) ^ ((r & 7) << 4);
      gl_lds16(Wbc + (long)r * 16384 + kb + sc, Bsm + o);
    }
    __syncthreads();
    short8 af[2][2], bfr[4][2];
    #pragma unroll
    for (int fr = 0; fr < 2; ++fr)
      #pragma unroll
      for (int ks = 0; ks < 2; ++ks) {
        int r = wm * 32 + fr * 16 + (lane & 15);
        int g = ks * 4 + (lane >> 4);
        int byt = r * 128 + ((g ^ (r & 7)) << 4);
        af[fr][ks] = *reinterpret_cast<const short8*>(Asm + byt);
      }
    #pragma unroll
    for (int fc = 0; fc < 4; ++fc)
      #pragma unroll
      for (int ks = 0; ks < 2; ++ks) {
        int n = wn * 64 + fc * 16 + (lane & 15);
        int g = ks * 4 + (lane >> 4);
        int byt = n * 128 + ((g ^ (n & 7)) << 4);
        bfr[fc][ks] = *reinterpret_cast<const short8*>(Bsm + byt);
      }
    #pragma unroll
    for (int fr = 0; fr < 2; ++fr)
      #pragma unroll
      for (int fc = 0; fc < 4; ++fc)
        #pragma unroll
        for (int ks = 0; ks < 2; ++ks)
          acc[fr][fc] = __builtin_amdgcn_mfma_f32_16x16x32_bf16(af[fr][ks], bfr[fc][ks],
                                                                acc[fr][fc], 0, 0, 0);
    __syncthreads();
  }
  float* p = part + (long)sp * 262144;
  #pragma unroll
  for (int fr = 0; fr < 2; ++fr)
    #pragma unroll
    for (int fc = 0; fc < 4; ++fc)
      #pragma unroll
      for (int r4 = 0; r4 < 4; ++r4) {
        int ii = i0 + wm * 32 + fr * 16 + (lane >> 4) * 4 + r4;  // C/D: row=(lane>>4)*4+reg
        int nn = wn * 64 + fc * 16 + (lane & 15);                 // C/D: col=lane&15
        p[(long)ii * 128 + nn] = acc[fr][fc][r4];
      }
}

// ---------------- reduce: sum 16 partials + bias, apply valid_i mask ----------------
__global__ __launch_bounds__(256) void sp_reduce(const float* __restrict__ part,
                                                 const float* __restrict__ bias,
                                                 const float* __restrict__ pos,
                                                 const int* __restrict__ mask,
                                                 float* __restrict__ out) {
  int g = blockIdx.x * 256 + threadIdx.x;  // 0..262143
  int i = g >> 7, n = g & 127;
  float acc = bias[n];
  #pragma unroll
  for (int s = 0; s < 16; ++s) acc += part[(long)s * 262144 + g];
  float px = pos[2 * i], py = pos[2 * i + 1];
  bool vi = (mask[i] != 0) && (px == px) && (py == py);  // mask & ~isnan(pos).any
  out[g] = vi ? acc : 0.f;
}

extern "C" void kernel_launch(void* const* d_in, const int* in_sizes, int n_in,
                              void* d_out, int out_size, void* d_ws, size_t ws_size,
                              hipStream_t stream) {
  const float* hidden  = (const float*)d_in[0];
  const float* pos     = (const float*)d_in[1];
  const int*   mask    = (const int*)d_in[2];   // bool input -> int32 per harness contract
  const float* W       = (const float*)d_in[3];
  const float* bias    = (const float*)d_in[4];
  char* ws = (char*)d_ws;
  __hip_bfloat16* hb   = (__hip_bfloat16*)(ws + O_HB);
  __hip_bfloat16* wb   = (__hip_bfloat16*)(ws + O_WB);
  __hip_bfloat16* grid = (__hip_bfloat16*)(ws + O_GRID);
  float* part          = (float*)(ws + O_PART);
  float2* posm         = (float2*)(ws + O_POSM);
  float* out           = (float*)d_out;

  sp_prep<<<1289, 256, 0, stream>>>(hidden, W, pos, mask, hb, wb, posm);
  sp_build<<<512, 256, 0, stream>>>(pos, posm, hb, grid);
  sp_gemm<<<512, 256, 0, stream>>>(grid, wb, part);
  sp_reduce<<<1024, 256, 0, stream>>>(part, bias, pos, mask, out);
}

// Round 9
// 82.037 us; speedup vs baseline: 12.6351x; 1.1220x over previous
//
#include <hip/hip_runtime.h>
#include <hip/hip_bf16.h>
#include <stdint.h>

// Problem constants: A=2048 agents, H=128, G=8 (64 cells), NB=32, CELL=8
// pooled = (grid[A,64,128] flattened) @ W.T + b ; out masked by valid_i.

typedef __attribute__((ext_vector_type(4))) float f32x4;
typedef __attribute__((ext_vector_type(8))) short short8;

// workspace layout (bytes)
#define O_HB   0u          // bf16 hidden [2049][128]  (row 2048 = zeros, dummy target)
#define O_WB   1048576u    // bf16 W      [128][8192]
#define O_GRID 3145728u    // bf16 grid   [2048][8192]
#define O_PART 36700160u   // f32 partials [16][2048][128] (written by gemm)
// The following overlay the O_PART region: they are fully consumed by sp_gather
// BEFORE sp_gemm writes part (stream-ordered kernels) -- no extra ws needed.
#define O_LIST 36700160u   // u32 lists [2048][1280] pre-multiplied byte offsets (10.5 MB)
#define O_OFFS 47185920u   // int offs  [2048][65]   per-cell exclusive offsets (532 KB)
#define O_POSM 47718400u   // float2 posm[2048] NaN-poisoned positions (16 KB)
// total ~51 MB (same requirement as previous rounds)

__device__ __forceinline__ void gl_lds16(const void* g, void* l) {
  __builtin_amdgcn_global_load_lds((const __attribute__((address_space(1))) void*)g,
                                   (__attribute__((address_space(3))) void*)l, 16, 0, 0);
}

__device__ __forceinline__ float bf_lo(uint32_t w) {
  union { uint32_t u; float f; } v{w << 16}; return v.f;
}
__device__ __forceinline__ float bf_hi(uint32_t w) {
  union { uint32_t u; float f; } v{w & 0xffff0000u}; return v.f;
}
__device__ __forceinline__ uint32_t pack_bf2(float x, float y) {
  __hip_bfloat16 bx = __float2bfloat16(x), by = __float2bfloat16(y);
  return ((uint32_t)(*(unsigned short*)&by) << 16) | (*(unsigned short*)&bx);
}

// ---------------- prep: f32 -> bf16 conversions + NaN-poisoned posm ----------------
__global__ __launch_bounds__(256) void sp_prep(const float* __restrict__ hidden,
                                               const float* __restrict__ W,
                                               const float* __restrict__ pos,
                                               const int* __restrict__ mask,
                                               __hip_bfloat16* __restrict__ hb,
                                               __hip_bfloat16* __restrict__ wb,
                                               float2* __restrict__ posm) {
  int idx = blockIdx.x * 256 + threadIdx.x;
  const int HID4 = (2049 * 128) / 4;   // 65568 groups of 4
  const int W4   = (128 * 8192) / 4;   // 262144 groups of 4
  if (idx < HID4) {
    int e = idx * 4;
    float4 v = make_float4(0.f, 0.f, 0.f, 0.f);
    if (e < 2048 * 128) v = *reinterpret_cast<const float4*>(hidden + e);
    ushort4 pk;
    pk.x = (ushort)(pack_bf2(v.x, v.x) & 0xffffu);
    pk.y = (ushort)(pack_bf2(v.y, v.y) & 0xffffu);
    pk.z = (ushort)(pack_bf2(v.z, v.z) & 0xffffu);
    pk.w = (ushort)(pack_bf2(v.w, v.w) & 0xffffu);
    *reinterpret_cast<ushort4*>(hb + e) = pk;
  } else if (idx < HID4 + W4) {
    int e = (idx - HID4) * 4;
    float4 v = *reinterpret_cast<const float4*>(W + e);
    ushort4 pk;
    pk.x = (ushort)(pack_bf2(v.x, v.x) & 0xffffu);
    pk.y = (ushort)(pack_bf2(v.y, v.y) & 0xffffu);
    pk.z = (ushort)(pack_bf2(v.z, v.z) & 0xffffu);
    pk.w = (ushort)(pack_bf2(v.w, v.w) & 0xffffu);
    *reinterpret_cast<ushort4*>(wb + e) = pk;
  } else {
    int j = idx - (HID4 + W4);
    if (j < 2048) {
      float2 p = reinterpret_cast<const float2*>(pos)[j];
      union { uint32_t u; float f; } qn{0x7fc00000u};  // quiet NaN
      float2 o;
      bool m = (mask[j] != 0);
      o.x = m ? p.x : qn.f;
      o.y = m ? p.y : qn.f;
      posm[j] = o;
    }
  }
}

// ---------------- bins: wave-per-agent counting sort -> GLOBAL lists ----------------
// 512 blocks x 256 (4 waves), one agent per wave, everything wave-private (no
// barriers; wave-own LDS rows; same-wave DS ordering is hazard-checked by HW).
// Writes: listG[i][slot] = j<<8 (pre-multiplied hb byte offset), cell-sorted,
// unpadded; offsG[i][c] = exclusive start of cell c, offsG[i][64] = total.
__global__ __launch_bounds__(256) void sp_bins(const float* __restrict__ pos,
                                               const float2* __restrict__ posm,
                                               uint32_t* __restrict__ listG,
                                               int* __restrict__ offsG) {
  __shared__ int hist[4][64];
  __shared__ int curs[4][64];
  int t = threadIdx.x;
  int wv = t >> 6;
  int lane = t & 63;
  int i = blockIdx.x * 4 + wv;           // this wave's agent
  float pxi = pos[2 * i], pyi = pos[2 * i + 1];
  hist[wv][lane] = 0;
  // Phase A: bin all 2048 j's; pack 32 bins into 8 regs (byte each, static idx)
  uint32_t bp[8];
  #pragma unroll
  for (int r = 0; r < 8; ++r) bp[r] = 0;
  #pragma unroll
  for (int ch = 0; ch < 32; ++ch) {
    int j = ch * 64 + lane;
    float2 pj = posm[j];
    float rx = pj.x - pxi, ry = pj.y - pyi;
    // NaN rel (masked-out j or NaN pos) -> comparisons false -> invalid
    bool ok = (fabsf(rx) < 32.f) && (fabsf(ry) < 32.f) && (j != i);
    uint32_t b = 255;
    if (ok) {
      // rx,ry in (-32,32): (rx+32)*0.125 in [0,8) exactly; clip is a no-op
      int col = (int)floorf((rx + 32.f) * 0.125f);
      int row = (int)floorf((ry + 32.f) * 0.125f);
      b = (uint32_t)(row * 8 + col);
      atomicAdd(&hist[wv][b], 1);        // int LDS atomic (native)
    }
    bp[ch >> 2] |= b << ((ch & 3) * 8);
  }
  // Phase B: wave shfl prefix scan over cell counts (lane = cell), unpadded
  int h = hist[wv][lane];
  int x = h;
  #pragma unroll
  for (int d = 1; d < 64; d <<= 1) {
    int y = __shfl_up(x, d);
    if (lane >= d) x += y;
  }
  int start = x - h;
  curs[wv][lane] = start;
  offsG[i * 65 + lane] = start;
  if (lane == 63) offsG[i * 65 + 64] = x;   // total
  // Phase C: scatter pre-multiplied byte offsets (intra-wave int atomics only)
  uint32_t* lrow = listG + (size_t)i * 1280;
  #pragma unroll
  for (int ch = 0; ch < 32; ++ch) {
    uint32_t b = (bp[ch >> 2] >> ((ch & 3) * 8)) & 255u;
    if (b != 255u) {
      int slot = atomicAdd(&curs[wv][b], 1);
      lrow[slot] = (uint32_t)(ch * 64 + lane) << 8;
    }
  }
}

// ---------------- gather: ONE WAVE PER (agent, cell) -- 131072 short chains --------
// 32768 blocks x 256, no LDS, no barriers. Wave: load offs (scalar), load up to
// 64 entries in one lane-parallel read, broadcast each via readlane(uniform k),
// gather rows 4-deep (independent loads, 4 acc streams), pack bf16, one
// coalesced 256B store. Empty cells store zeros. ~32 waves/CU resident; per-wave
// chain ~1K cyc; latency hidden by 16x oversubscription.
__global__ __launch_bounds__(256) void sp_gather(const uint32_t* __restrict__ listG,
                                                 const int* __restrict__ offsG,
                                                 const __hip_bfloat16* __restrict__ hb,
                                                 __hip_bfloat16* __restrict__ grid) {
  int t = threadIdx.x;
  int wv = __builtin_amdgcn_readfirstlane(t >> 6);   // scalarize wave id
  int lane = t & 63;
  int g = blockIdx.x * 4 + wv;
  int i = g >> 6;          // agent
  int c = g & 63;          // cell
  int s0 = offsG[i * 65 + c];
  int s1 = offsG[i * 65 + c + 1];
  int n = s1 - s0;
  const uint32_t* lp = listG + (size_t)i * 1280 + s0;
  const char* hbB = reinterpret_cast<const char*>(hb);
  int l4 = lane * 4;
  float a0 = 0.f, a1 = 0.f, b0 = 0.f, b1 = 0.f;
  float c0 = 0.f, c1 = 0.f, d0 = 0.f, d1 = 0.f;
  for (int chunk = 0; chunk < n; chunk += 64) {
    int rem = n - chunk;
    int m = rem < 64 ? rem : 64;
    uint32_t ev = lp[chunk + (lane < m ? lane : 0)];  // lane k holds entry chunk+k
    int k = 0;
    for (; k + 4 <= m; k += 4) {
      uint32_t o0 = (uint32_t)__builtin_amdgcn_readlane((int)ev, k);
      uint32_t o1 = (uint32_t)__builtin_amdgcn_readlane((int)ev, k + 1);
      uint32_t o2 = (uint32_t)__builtin_amdgcn_readlane((int)ev, k + 2);
      uint32_t o3 = (uint32_t)__builtin_amdgcn_readlane((int)ev, k + 3);
      uint32_t w0 = *reinterpret_cast<const uint32_t*>(hbB + o0 + l4);
      uint32_t w1 = *reinterpret_cast<const uint32_t*>(hbB + o1 + l4);
      uint32_t w2 = *reinterpret_cast<const uint32_t*>(hbB + o2 + l4);
      uint32_t w3 = *reinterpret_cast<const uint32_t*>(hbB + o3 + l4);
      a0 += bf_lo(w0); a1 += bf_hi(w0);
      b0 += bf_lo(w1); b1 += bf_hi(w1);
      c0 += bf_lo(w2); c1 += bf_hi(w2);
      d0 += bf_lo(w3); d1 += bf_hi(w3);
    }
    for (; k < m; ++k) {
      uint32_t o0 = (uint32_t)__builtin_amdgcn_readlane((int)ev, k);
      uint32_t w0 = *reinterpret_cast<const uint32_t*>(hbB + o0 + l4);
      a0 += bf_lo(w0); a1 += bf_hi(w0);
    }
  }
  float rx = (a0 + b0) + (c0 + d0);
  float ry = (a1 + b1) + (c1 + d1);
  uint32_t pk = pack_bf2(rx, ry);   // cols 2*lane, 2*lane+1
  *reinterpret_cast<uint32_t*>(
      reinterpret_cast<char*>(grid) + (((size_t)i << 14) + (c << 8) + l4)) = pk;
}

// ---------------- gemm: [2048 x 8192] bf16 @ W[n][k] bf16 -> f32 partials (split-K 16) ----------------
// BM=64, BN=128, BK=64; 4 waves, wave-tile 32x64; mfma_f32_16x16x32_bf16
// LDS rows are 128 B = 8 x 16B granules; XOR-swizzle granule with (row&7):
// stage source pre-swizzled (linear LDS dest, per global_load_lds constraint), read with same XOR.
__global__ __launch_bounds__(256) void sp_gemm(const __hip_bfloat16* __restrict__ Ag,
                                               const __hip_bfloat16* __restrict__ Wb,
                                               float* __restrict__ part) {
  __shared__ __align__(16) char Asm[8192];    // A tile [64][64] bf16
  __shared__ __align__(16) char Bsm[16384];   // B tile [128][64] bf16 (n-major)
  int t = threadIdx.x;
  int lane = t & 63;
  int w = t >> 6;
  int wm = w >> 1, wn = w & 1;
  int bx = blockIdx.x;
  int mt = bx & 31;     // 32 M-tiles of 64 rows
  int sp = bx >> 5;     // 16 K-splits of 512
  int i0 = mt * 64;
  long kbase = (long)sp * 512 * 2;  // byte offset of K-chunk within a row
  const char* Agc = (const char*)Ag;
  const char* Wbc = (const char*)Wb;
  f32x4 acc[2][4] = {};
  for (int st = 0; st < 8; ++st) {   // 8 K-steps of 64
    long kb = kbase + st * 128;
    #pragma unroll
    for (int q = 0; q < 2; ++q) {    // A: 8 KB
      int o = (q * 256 + t) * 16;
      int r = o >> 7;
      int sc = (o & 127) ^ ((r & 7) << 4);
      gl_lds16(Agc + (long)(i0 + r) * 16384 + kb + sc, Asm + o);
    }
    #pragma unroll
    for (int q = 0; q < 4; ++q) {    // B: 16 KB
      int o = (q * 256 + t) * 16;
      int r = o >> 7;
      int sc = (o & 127) ^ ((r & 7) << 4);
      gl_lds16(Wbc + (long)r * 16384 + kb + sc, Bsm + o);
    }
    __syncthreads();
    short8 af[2][2], bfr[4][2];
    #pragma unroll
    for (int fr = 0; fr < 2; ++fr)
      #pragma unroll
      for (int ks = 0; ks < 2; ++ks) {
        int r = wm * 32 + fr * 16 + (lane & 15);
        int g = ks * 4 + (lane >> 4);
        int byt = r * 128 + ((g ^ (r & 7)) << 4);
        af[fr][ks] = *reinterpret_cast<const short8*>(Asm + byt);
      }
    #pragma unroll
    for (int fc = 0; fc < 4; ++fc)
      #pragma unroll
      for (int ks = 0; ks < 2; ++ks) {
        int n = wn * 64 + fc * 16 + (lane & 15);
        int g = ks * 4 + (lane >> 4);
        int byt = n * 128 + ((g ^ (n & 7)) << 4);
        bfr[fc][ks] = *reinterpret_cast<const short8*>(Bsm + byt);
      }
    #pragma unroll
    for (int fr = 0; fr < 2; ++fr)
      #pragma unroll
      for (int fc = 0; fc < 4; ++fc)
        #pragma unroll
        for (int ks = 0; ks < 2; ++ks)
          acc[fr][fc] = __builtin_amdgcn_mfma_f32_16x16x32_bf16(af[fr][ks], bfr[fc][ks],
                                                                acc[fr][fc], 0, 0, 0);
    __syncthreads();
  }
  float* p = part + (long)sp * 262144;
  #pragma unroll
  for (int fr = 0; fr < 2; ++fr)
    #pragma unroll
    for (int fc = 0; fc < 4; ++fc)
      #pragma unroll
      for (int r4 = 0; r4 < 4; ++r4) {
        int ii = i0 + wm * 32 + fr * 16 + (lane >> 4) * 4 + r4;  // C/D: row=(lane>>4)*4+reg
        int nn = wn * 64 + fc * 16 + (lane & 15);                 // C/D: col=lane&15
        p[(long)ii * 128 + nn] = acc[fr][fc][r4];
      }
}

// ---------------- reduce: sum 16 partials + bias, apply valid_i mask ----------------
__global__ __launch_bounds__(256) void sp_reduce(const float* __restrict__ part,
                                                 const float* __restrict__ bias,
                                                 const float* __restrict__ pos,
                                                 const int* __restrict__ mask,
                                                 float* __restrict__ out) {
  int g = blockIdx.x * 256 + threadIdx.x;  // 0..262143
  int i = g >> 7, n = g & 127;
  float acc = bias[n];
  #pragma unroll
  for (int s = 0; s < 16; ++s) acc += part[(long)s * 262144 + g];
  float px = pos[2 * i], py = pos[2 * i + 1];
  bool vi = (mask[i] != 0) && (px == px) && (py == py);  // mask & ~isnan(pos).any
  out[g] = vi ? acc : 0.f;
}

extern "C" void kernel_launch(void* const* d_in, const int* in_sizes, int n_in,
                              void* d_out, int out_size, void* d_ws, size_t ws_size,
                              hipStream_t stream) {
  const float* hidden  = (const float*)d_in[0];
  const float* pos     = (const float*)d_in[1];
  const int*   mask    = (const int*)d_in[2];   // bool input -> int32 per harness contract
  const float* W       = (const float*)d_in[3];
  const float* bias    = (const float*)d_in[4];
  char* ws = (char*)d_ws;
  __hip_bfloat16* hb   = (__hip_bfloat16*)(ws + O_HB);
  __hip_bfloat16* wb   = (__hip_bfloat16*)(ws + O_WB);
  __hip_bfloat16* grid = (__hip_bfloat16*)(ws + O_GRID);
  float* part          = (float*)(ws + O_PART);
  uint32_t* listG      = (uint32_t*)(ws + O_LIST);
  int* offsG           = (int*)(ws + O_OFFS);
  float2* posm         = (float2*)(ws + O_POSM);
  float* out           = (float*)d_out;

  sp_prep<<<1289, 256, 0, stream>>>(hidden, W, pos, mask, hb, wb, posm);
  sp_bins<<<512, 256, 0, stream>>>(pos, posm, listG, offsG);
  sp_gather<<<32768, 256, 0, stream>>>(listG, offsG, hb, grid);
  sp_gemm<<<512, 256, 0, stream>>>(grid, wb, part);
  sp_reduce<<<1024, 256, 0, stream>>>(part, bias, pos, mask, out);
}